// Round 1
// baseline (871.504 us; speedup 1.0000x reference)
//
#include <hip/hip_runtime.h>

// ---------------------------------------------------------------------------
// GCN pipeline:
//   hs1 = (x @ W1) * dinv[row]                      (gemm_kernel<128,4,SCALE>)
//   h1  = relu(LN(dinv*(sum_{e->n} hs1[src] + hs1[n]) + b1))   (aggregate_ln)
//   hs2 = (h1 @ W2) * dinv[row]
//   h2  = relu(LN(... + b2))
//   G   = relu(h2 @ Wg1 + bg1)                      (gemm_kernel<64,2,BIASRELU>)
//   gate= G @ Wg2 + bg2                             (gate_dot)
//   out = segment_softmax_pool(h2, gate) @ Wc + bc  (pool_kernel, batch sorted)
// CSR (by dst) built per launch: count -> 3-kernel scan -> place.
// ---------------------------------------------------------------------------

// ---------------- CSR build ----------------
__global__ __launch_bounds__(256) void count_edges_kernel(
    const int* __restrict__ dst, int* __restrict__ counts, int E) {
  int e = blockIdx.x * 256 + threadIdx.x;
  if (e < E) atomicAdd(&counts[dst[e]], 1);
}

__global__ __launch_bounds__(256) void dinv_kernel(
    const int* __restrict__ counts, float* __restrict__ dinv, int N) {
  int n = blockIdx.x * 256 + threadIdx.x;
  if (n < N) dinv[n] = rsqrtf((float)(counts[n] + 1));  // +1 self loop
}

__global__ __launch_bounds__(256) void scan_partials_kernel(
    const int* __restrict__ counts, int* __restrict__ partials, int N) {
  __shared__ int s[256];
  int b = blockIdx.x, t = threadIdx.x;
  int base = b * 1024 + t * 4;
  int sum = 0;
  for (int i = 0; i < 4; ++i) {
    int idx = base + i;
    if (idx < N) sum += counts[idx];
  }
  s[t] = sum;
  __syncthreads();
  for (int off = 128; off; off >>= 1) {
    if (t < off) s[t] += s[t + off];
    __syncthreads();
  }
  if (t == 0) partials[b] = s[0];
}

__global__ __launch_bounds__(128) void scan_tops_kernel(
    int* __restrict__ partials, int* __restrict__ row_start, int nblk, int N) {
  __shared__ int s[128];
  int t = threadIdx.x;
  int v = t < nblk ? partials[t] : 0;
  s[t] = v;
  __syncthreads();
  for (int off = 1; off < 128; off <<= 1) {
    int x = (t >= off) ? s[t - off] : 0;
    __syncthreads();
    s[t] += x;
    __syncthreads();
  }
  if (t < nblk) partials[t] = s[t] - v;  // exclusive
  if (t == 127) row_start[N] = s[127];   // total == E
}

__global__ __launch_bounds__(256) void scan_block_kernel(
    const int* __restrict__ counts, const int* __restrict__ partials,
    int* __restrict__ row_start, int N) {
  __shared__ int s[256];
  int b = blockIdx.x, t = threadIdx.x;
  int base = b * 1024 + t * 4;
  int v[4];
  int sum = 0;
  for (int i = 0; i < 4; ++i) {
    int idx = base + i;
    v[i] = idx < N ? counts[idx] : 0;
    sum += v[i];
  }
  s[t] = sum;
  __syncthreads();
  for (int off = 1; off < 256; off <<= 1) {
    int x = (t >= off) ? s[t - off] : 0;
    __syncthreads();
    s[t] += x;
    __syncthreads();
  }
  int excl = s[t] - sum + partials[b];
  for (int i = 0; i < 4; ++i) {
    int idx = base + i;
    if (idx < N) row_start[idx] = excl;
    excl += v[i];
  }
}

__global__ __launch_bounds__(256) void place_edges_kernel(
    const int* __restrict__ src, const int* __restrict__ dst,
    const int* __restrict__ row_start, int* __restrict__ fill,
    int* __restrict__ srcs, int E) {
  int e = blockIdx.x * 256 + threadIdx.x;
  if (e < E) {
    int d = dst[e];
    int pos = row_start[d] + atomicAdd(&fill[d], 1);
    srcs[pos] = src[e];
  }
}

// ---------------- GEMM (K=128 fixed), fused epilogues ----------------
// NC: output cols (128 or 64). MR: micro rows. 256 threads, TM = 64 rows/block.
template <int NC, int MR, bool SCALE, bool BIASRELU>
__global__ __launch_bounds__(256) void gemm_kernel(
    const float* __restrict__ in, const float* __restrict__ W,
    const float* __restrict__ bias, const float* __restrict__ dinv,
    float* __restrict__ out, int M) {
  constexpr int CG = NC / 8;       // col groups (16 or 8)
  constexpr int STRIDE = 132;      // 128 + 4 pad -> 2-way LDS aliasing only
  constexpr int TM = (256 / CG) * MR;  // 64 for both configs
  __shared__ float xS[TM * STRIDE];
  const int t = threadIdx.x;
  const int row0 = blockIdx.x * TM;

  // stage x tile [TM][128] (coalesced float4 global loads)
#pragma unroll
  for (int i = 0; i < TM / 8; ++i) {
    int f4 = t + i * 256;          // [0, TM*32)
    int r = f4 >> 5;
    int k4 = (f4 & 31) << 2;
    float4 v = make_float4(0.f, 0.f, 0.f, 0.f);
    int row = row0 + r;
    if (row < M) v = *(const float4*)(in + (size_t)row * 128 + k4);
    *(float4*)&xS[r * STRIDE + k4] = v;
  }
  __syncthreads();

  const int cg = t % CG, rg = t / CG;
  const int c0 = cg * 8, r0 = rg * MR;
  float acc[MR][8];
#pragma unroll
  for (int r = 0; r < MR; ++r)
#pragma unroll
    for (int c = 0; c < 8; ++c) acc[r][c] = 0.f;

  for (int k = 0; k < 128; k += 4) {
    float4 a[MR];
#pragma unroll
    for (int r = 0; r < MR; ++r)
      a[r] = *(const float4*)&xS[(r0 + r) * STRIDE + k];
    float4 w0[4], w1[4];
#pragma unroll
    for (int kk = 0; kk < 4; ++kk) {
      w0[kk] = *(const float4*)(W + (size_t)(k + kk) * NC + c0);
      w1[kk] = *(const float4*)(W + (size_t)(k + kk) * NC + c0 + 4);
    }
#pragma unroll
    for (int kk = 0; kk < 4; ++kk) {
#pragma unroll
      for (int r = 0; r < MR; ++r) {
        float av = kk == 0 ? a[r].x : kk == 1 ? a[r].y : kk == 2 ? a[r].z : a[r].w;
        acc[r][0] = fmaf(av, w0[kk].x, acc[r][0]);
        acc[r][1] = fmaf(av, w0[kk].y, acc[r][1]);
        acc[r][2] = fmaf(av, w0[kk].z, acc[r][2]);
        acc[r][3] = fmaf(av, w0[kk].w, acc[r][3]);
        acc[r][4] = fmaf(av, w1[kk].x, acc[r][4]);
        acc[r][5] = fmaf(av, w1[kk].y, acc[r][5]);
        acc[r][6] = fmaf(av, w1[kk].z, acc[r][6]);
        acc[r][7] = fmaf(av, w1[kk].w, acc[r][7]);
      }
    }
  }

  float bv[8];
  if constexpr (BIASRELU) {
    float4 bb0 = *(const float4*)(bias + c0);
    float4 bb1 = *(const float4*)(bias + c0 + 4);
    bv[0] = bb0.x; bv[1] = bb0.y; bv[2] = bb0.z; bv[3] = bb0.w;
    bv[4] = bb1.x; bv[5] = bb1.y; bv[6] = bb1.z; bv[7] = bb1.w;
  }
#pragma unroll
  for (int r = 0; r < MR; ++r) {
    int row = row0 + r0 + r;
    if (row < M) {
      float mult = 1.f;
      if constexpr (SCALE) mult = dinv[row];
      float o[8];
#pragma unroll
      for (int c = 0; c < 8; ++c) {
        float v = acc[r][c] * mult;
        if constexpr (BIASRELU) v = fmaxf(acc[r][c] + bv[c], 0.f);
        o[c] = v;
      }
      *(float4*)(out + (size_t)row * NC + c0) = make_float4(o[0], o[1], o[2], o[3]);
      *(float4*)(out + (size_t)row * NC + c0 + 4) = make_float4(o[4], o[5], o[6], o[7]);
    }
  }
}

// ---------------- gather + dinv + bias + LayerNorm + ReLU ----------------
// one wave per node; float2 per lane covers HID=128
__global__ __launch_bounds__(256) void aggregate_ln_kernel(
    const float* __restrict__ hs, const int* __restrict__ row_start,
    const int* __restrict__ srcs, const float* __restrict__ dinv,
    const float* __restrict__ bias, const float* __restrict__ gamma,
    const float* __restrict__ beta, float* __restrict__ out, int N) {
  int n = (blockIdx.x * 256 + threadIdx.x) >> 6;
  int lane = threadIdx.x & 63;
  if (n >= N) return;
  const float2* hs2 = (const float2*)hs;
  size_t idx = (size_t)n * 64 + lane;
  float2 self = hs2[idx];
  float ax = self.x, ay = self.y;  // self loop term
  int beg = row_start[n], end = row_start[n + 1];
  int i = beg;
  for (; i + 4 <= end; i += 4) {
    int s0 = srcs[i], s1 = srcs[i + 1], s2 = srcs[i + 2], s3 = srcs[i + 3];
    float2 v0 = hs2[(size_t)s0 * 64 + lane];
    float2 v1 = hs2[(size_t)s1 * 64 + lane];
    float2 v2 = hs2[(size_t)s2 * 64 + lane];
    float2 v3 = hs2[(size_t)s3 * 64 + lane];
    ax += v0.x + v1.x + v2.x + v3.x;
    ay += v0.y + v1.y + v2.y + v3.y;
  }
  for (; i < end; ++i) {
    int s = srcs[i];
    float2 v = hs2[(size_t)s * 64 + lane];
    ax += v.x;
    ay += v.y;
  }
  float dv = dinv[n];
  float2 bb = *(const float2*)(bias + 2 * lane);
  float yx = ax * dv + bb.x;
  float yy = ay * dv + bb.y;
  float s1 = yx + yy, s2v = yx * yx + yy * yy;
  for (int off = 32; off; off >>= 1) {
    s1 += __shfl_xor(s1, off);
    s2v += __shfl_xor(s2v, off);
  }
  float mu = s1 * (1.f / 128.f);
  float var = s2v * (1.f / 128.f) - mu * mu;
  float rinv = rsqrtf(var + 1e-5f);
  float2 gg = *(const float2*)(gamma + 2 * lane);
  float2 be = *(const float2*)(beta + 2 * lane);
  float o0 = (yx - mu) * rinv * gg.x + be.x;
  float o1 = (yy - mu) * rinv * gg.y + be.y;
  float2 o = make_float2(fmaxf(o0, 0.f), fmaxf(o1, 0.f));
  ((float2*)out)[idx] = o;
}

// ---------------- gate = G @ Wg2 + bg2 (wave per node) ----------------
__global__ __launch_bounds__(256) void gate_dot_kernel(
    const float* __restrict__ G, const float* __restrict__ Wg2,
    const float* __restrict__ bg2, float* __restrict__ gate, int N) {
  int n = (blockIdx.x * 256 + threadIdx.x) >> 6;
  int lane = threadIdx.x & 63;
  if (n >= N) return;
  float v = G[(size_t)n * 64 + lane] * Wg2[lane];
  for (int off = 32; off; off >>= 1) v += __shfl_xor(v, off);
  if (lane == 0) gate[n] = v + bg2[0];
}

// ---------------- segment softmax pool + classifier ----------------
__device__ inline int lower_bound_i(const int* a, int n, int key) {
  int lo = 0, hi = n;
  while (lo < hi) {
    int mid = (lo + hi) >> 1;
    if (a[mid] < key) lo = mid + 1; else hi = mid;
  }
  return lo;
}

__global__ __launch_bounds__(256) void pool_kernel(
    const float* __restrict__ h2, const float* __restrict__ gate,
    const int* __restrict__ batch, const float* __restrict__ Wc,
    const float* __restrict__ bc, float* __restrict__ out, int N) {
  int g = blockIdx.x, t = threadIdx.x;
  __shared__ float red[256];
  __shared__ float pooled[128];
  __shared__ float s_gmax, s_inv;
  int lo = lower_bound_i(batch, N, g);
  int hi = lower_bound_i(batch, N, g + 1);
  // pass 1: max gate
  float m = -3.4e38f;
  for (int i = lo + t; i < hi; i += 256) m = fmaxf(m, gate[i]);
  red[t] = m;
  __syncthreads();
  for (int off = 128; off; off >>= 1) {
    if (t < off) red[t] = fmaxf(red[t], red[t + off]);
    __syncthreads();
  }
  if (t == 0) s_gmax = red[0];
  __syncthreads();
  float gmax = s_gmax;
  __syncthreads();
  // pass 2: denom
  float ssum = 0.f;
  for (int i = lo + t; i < hi; i += 256) ssum += expf(gate[i] - gmax);
  red[t] = ssum;
  __syncthreads();
  for (int off = 128; off; off >>= 1) {
    if (t < off) red[t] += red[t + off];
    __syncthreads();
  }
  if (t == 0) s_inv = red[0] > 0.f ? 1.f / red[0] : 0.f;
  __syncthreads();
  float inv = s_inv;
  __syncthreads();
  // pass 3: weighted feature sum (2 node streams x 128 features)
  int f = t & 127, half = t >> 7;
  float acc = 0.f;
  int i = lo + half;
  for (; i + 8 <= hi; i += 8) {
    float e0 = expf(gate[i] - gmax);
    float e1 = expf(gate[i + 2] - gmax);
    float e2 = expf(gate[i + 4] - gmax);
    float e3 = expf(gate[i + 6] - gmax);
    float v0 = h2[(size_t)i * 128 + f];
    float v1 = h2[(size_t)(i + 2) * 128 + f];
    float v2 = h2[(size_t)(i + 4) * 128 + f];
    float v3 = h2[(size_t)(i + 6) * 128 + f];
    acc += e0 * v0 + e1 * v1 + e2 * v2 + e3 * v3;
  }
  for (; i < hi; i += 2) acc += expf(gate[i] - gmax) * h2[(size_t)i * 128 + f];
  red[t] = acc;
  __syncthreads();
  if (t < 128) pooled[t] = (red[t] + red[t + 128]) * inv;
  __syncthreads();
  // classifier: out[g][c] = pooled . Wc[:,c] + bc[c]
  if (t < 16) {
    float o = bc[t];
    for (int ff = 0; ff < 128; ++ff) o = fmaf(pooled[ff], Wc[ff * 16 + t], o);
    out[g * 16 + t] = o;
  }
}

// ---------------- host launcher ----------------
extern "C" void kernel_launch(void* const* d_in, const int* in_sizes, int n_in,
                              void* d_out, int out_size, void* d_ws, size_t ws_size,
                              hipStream_t stream) {
  const float* x   = (const float*)d_in[0];
  const int*   ei  = (const int*)d_in[1];
  const int*   bat = (const int*)d_in[2];
  const float* W1  = (const float*)d_in[3];
  const float* b1  = (const float*)d_in[4];
  const float* g1  = (const float*)d_in[5];
  const float* be1 = (const float*)d_in[6];
  const float* W2  = (const float*)d_in[7];
  const float* b2  = (const float*)d_in[8];
  const float* g2  = (const float*)d_in[9];
  const float* be2 = (const float*)d_in[10];
  const float* Wg1 = (const float*)d_in[11];
  const float* bg1 = (const float*)d_in[12];
  const float* Wg2 = (const float*)d_in[13];
  const float* bg2 = (const float*)d_in[14];
  const float* Wc  = (const float*)d_in[15];
  const float* bc  = (const float*)d_in[16];

  const int N = in_sizes[0] / 128;
  const int E = in_sizes[1] / 2;
  const int B = out_size / 16;
  const int* src = ei;
  const int* dst = ei + E;

  const int Np = (N + 3) & ~3;
  const int Ep = (E + 3) & ~3;

  int* counts   = (int*)d_ws;          // Np (zeroed)
  int* fill     = counts + Np;         // Np (zeroed)
  int* rs       = fill + Np;           // Np + 4 (row_start, N+1 used)
  int* partials = rs + Np + 4;         // 128
  int* srcs     = partials + 128;      // Ep
  float* dinv   = (float*)(srcs + Ep); // Np
  float* hs     = dinv + Np;           // 128*N  (also reused as G / gate later)
  float* h1     = hs + (size_t)128 * N;  // 128*N (h1, later h2)
  float* Gbuf   = hs;                    // N*64, overlays dead hs
  float* gatep  = hs + (size_t)64 * N;   // N

  hipMemsetAsync(counts, 0, sizeof(int) * 2 * (size_t)Np, stream);

  const int nblk = (N + 1023) / 1024;
  count_edges_kernel<<<(E + 255) / 256, 256, 0, stream>>>(dst, counts, E);
  dinv_kernel<<<(N + 255) / 256, 256, 0, stream>>>(counts, dinv, N);
  scan_partials_kernel<<<nblk, 256, 0, stream>>>(counts, partials, N);
  scan_tops_kernel<<<1, 128, 0, stream>>>(partials, rs, nblk, N);
  scan_block_kernel<<<nblk, 256, 0, stream>>>(counts, partials, rs, N);
  place_edges_kernel<<<(E + 255) / 256, 256, 0, stream>>>(src, dst, rs, fill, srcs, E);

  // conv1
  gemm_kernel<128, 4, true, false><<<(N + 63) / 64, 256, 0, stream>>>(
      x, W1, nullptr, dinv, hs, N);
  aggregate_ln_kernel<<<(N + 3) / 4, 256, 0, stream>>>(
      hs, rs, srcs, dinv, b1, g1, be1, h1, N);
  // conv2 (hs reused for hs2; h2 written over h1)
  gemm_kernel<128, 4, true, false><<<(N + 63) / 64, 256, 0, stream>>>(
      h1, W2, nullptr, dinv, hs, N);
  aggregate_ln_kernel<<<(N + 3) / 4, 256, 0, stream>>>(
      hs, rs, srcs, dinv, b2, g2, be2, h1, N);
  // gate MLP: G = relu(h2 @ Wg1 + bg1)  (G overlays dead hs)
  gemm_kernel<64, 2, false, true><<<(N + 63) / 64, 256, 0, stream>>>(
      h1, Wg1, bg1, nullptr, Gbuf, N);
  gate_dot_kernel<<<(N + 3) / 4, 256, 0, stream>>>(Gbuf, Wg2, bg2, gatep, N);
  // pool + classifier
  pool_kernel<<<B, 256, 0, stream>>>(h1, gatep, bat, Wc, bc, (float*)d_out, N);
}

// Round 2
// 637.565 us; speedup vs baseline: 1.3669x; 1.3669x over previous
//
#include <hip/hip_runtime.h>

// ---------------------------------------------------------------------------
// GCN pipeline (bf16 message/feature buffers, fp32 accumulation everywhere):
//   prep: W1t/W2t/Wg1t = transpose(W) as bf16 [n][k]
//   hs1 = bf16((x @ W1) * dinv[row])              gemm_mfma<128,...,f32-in>
//   h1  = bf16(relu(LN(dinv*(sum hs1[src] + hs1[n]) + b1)))  aggregate_ln
//   hs2 = bf16((h1 @ W2) * dinv[row])             gemm_mfma<128,...,bf16-in>
//   h2  = bf16(relu(LN(...)))
//   G   = bf16(relu(h2 @ Wg1 + bg1))              gemm_mfma<64,...>
//   gate= G . Wg2 + bg2                           gate_dot
//   out = segment_softmax_pool(h2, gate) @ Wc+bc  pool_kernel (batch sorted)
// CSR by dst built per launch: count -> scan -> place.
// ---------------------------------------------------------------------------

typedef unsigned short ushort_t;
typedef unsigned int uint_t;
typedef __attribute__((ext_vector_type(8))) short short8;   // 8 x bf16
typedef __attribute__((ext_vector_type(4))) float floatx4;  // MFMA acc

__device__ inline ushort_t bf16_rn(float f) {
  uint_t u = __float_as_uint(f);
  u += 0x7fffu + ((u >> 16) & 1u);  // round-nearest-even (finite inputs)
  return (ushort_t)(u >> 16);
}
__device__ inline float bf16_lo(uint_t v) { return __uint_as_float(v << 16); }
__device__ inline float bf16_hi(uint_t v) { return __uint_as_float(v & 0xffff0000u); }
__device__ inline uint_t bf16_pack(float a, float b) {
  return (uint_t)bf16_rn(a) | ((uint_t)bf16_rn(b) << 16);
}

// ---------------- CSR build ----------------
__global__ __launch_bounds__(256) void count_edges_kernel(
    const int* __restrict__ dst, int* __restrict__ counts, int E) {
  int e = blockIdx.x * 256 + threadIdx.x;
  if (e < E) atomicAdd(&counts[dst[e]], 1);
}

__global__ __launch_bounds__(256) void dinv_kernel(
    const int* __restrict__ counts, float* __restrict__ dinv, int N) {
  int n = blockIdx.x * 256 + threadIdx.x;
  if (n < N) dinv[n] = rsqrtf((float)(counts[n] + 1));  // +1 self loop
}

__global__ __launch_bounds__(256) void scan_partials_kernel(
    const int* __restrict__ counts, int* __restrict__ partials, int N) {
  __shared__ int s[256];
  int b = blockIdx.x, t = threadIdx.x;
  int base = b * 1024 + t * 4;
  int sum = 0;
  for (int i = 0; i < 4; ++i) {
    int idx = base + i;
    if (idx < N) sum += counts[idx];
  }
  s[t] = sum;
  __syncthreads();
  for (int off = 128; off; off >>= 1) {
    if (t < off) s[t] += s[t + off];
    __syncthreads();
  }
  if (t == 0) partials[b] = s[0];
}

__global__ __launch_bounds__(128) void scan_tops_kernel(
    int* __restrict__ partials, int* __restrict__ row_start, int nblk, int N) {
  __shared__ int s[128];
  int t = threadIdx.x;
  int v = t < nblk ? partials[t] : 0;
  s[t] = v;
  __syncthreads();
  for (int off = 1; off < 128; off <<= 1) {
    int x = (t >= off) ? s[t - off] : 0;
    __syncthreads();
    s[t] += x;
    __syncthreads();
  }
  if (t < nblk) partials[t] = s[t] - v;  // exclusive
  if (t == 127) row_start[N] = s[127];   // total == E
}

__global__ __launch_bounds__(256) void scan_block_kernel(
    const int* __restrict__ counts, const int* __restrict__ partials,
    int* __restrict__ row_start, int N) {
  __shared__ int s[256];
  int b = blockIdx.x, t = threadIdx.x;
  int base = b * 1024 + t * 4;
  int v[4];
  int sum = 0;
  for (int i = 0; i < 4; ++i) {
    int idx = base + i;
    v[i] = idx < N ? counts[idx] : 0;
    sum += v[i];
  }
  s[t] = sum;
  __syncthreads();
  for (int off = 1; off < 256; off <<= 1) {
    int x = (t >= off) ? s[t - off] : 0;
    __syncthreads();
    s[t] += x;
    __syncthreads();
  }
  int excl = s[t] - sum + partials[b];
  for (int i = 0; i < 4; ++i) {
    int idx = base + i;
    if (idx < N) row_start[idx] = excl;
    excl += v[i];
  }
}

__global__ __launch_bounds__(256) void place_edges_kernel(
    const int* __restrict__ src, const int* __restrict__ dst,
    const int* __restrict__ row_start, int* __restrict__ fill,
    int* __restrict__ srcs, int E) {
  int e = blockIdx.x * 256 + threadIdx.x;
  if (e < E) {
    int d = dst[e];
    int pos = row_start[d] + atomicAdd(&fill[d], 1);
    srcs[pos] = src[e];
  }
}

// ---------------- weight prep: Wt[n][k] = bf16(W[k][n]) ----------------
// grid 320 x 128 threads: b<128 -> W1 (128x128), b<256 -> W2, else Wg1 (128x64)
__global__ __launch_bounds__(128) void prep_weights_kernel(
    const float* __restrict__ W1, const float* __restrict__ W2,
    const float* __restrict__ Wg1, ushort_t* __restrict__ Wt) {
  int b = blockIdx.x, t = threadIdx.x;
  if (b < 128) {
    Wt[b * 128 + t] = bf16_rn(W1[t * 128 + b]);
  } else if (b < 256) {
    int n = b - 128;
    Wt[16384 + n * 128 + t] = bf16_rn(W2[t * 128 + n]);
  } else {
    int n = b - 256;
    Wt[32768 + n * 128 + t] = bf16_rn(Wg1[t * 64 + n]);
  }
}

// ---------------- MFMA GEMM: out[M][NC] = bf16(epilogue(in[M][128] @ W)) ----
// Wt is bf16 [NC][128] (pre-transposed). 256 threads, 128 rows/block.
// MFMA 16x16x32 bf16: A[m=lane&15][k=quad*8+j], B[k=quad*8+j][n=lane&15],
// D[row=quad*4+reg][col=lane&15].
template <int NC, bool SCALE, bool BIASRELU, bool IN_F32>
__global__ __launch_bounds__(256) void gemm_mfma_kernel(
    const void* __restrict__ in, const ushort_t* __restrict__ Wt,
    const float* __restrict__ bias, const float* __restrict__ dinv,
    ushort_t* __restrict__ out, int M) {
  constexpr int CT = NC / 16;  // col tiles (8 or 4)
  __shared__ short As[128 * 136];  // stride 136 shorts = 272B (16B-aligned, no pow2 bank stride)
  const int t = threadIdx.x;
  const int row0 = blockIdx.x * 128;

  // stage A tile: 128 rows x 128 elems as bf16
#pragma unroll
  for (int i = 0; i < 8; ++i) {
    int chunk = t + i * 256;     // 0..2047, 16 chunks of 8 elems per row
    int r = chunk >> 4;
    int c8 = (chunk & 15) * 8;
    int row = row0 + r;
    short8 val = {0, 0, 0, 0, 0, 0, 0, 0};
    if (IN_F32) {
      const float* inf = (const float*)in;
      if (row < M) {
        float4 v0 = *(const float4*)(inf + (size_t)row * 128 + c8);
        float4 v1 = *(const float4*)(inf + (size_t)row * 128 + c8 + 4);
        val[0] = (short)bf16_rn(v0.x); val[1] = (short)bf16_rn(v0.y);
        val[2] = (short)bf16_rn(v0.z); val[3] = (short)bf16_rn(v0.w);
        val[4] = (short)bf16_rn(v1.x); val[5] = (short)bf16_rn(v1.y);
        val[6] = (short)bf16_rn(v1.z); val[7] = (short)bf16_rn(v1.w);
      }
    } else {
      const short* inb = (const short*)in;
      if (row < M) val = *(const short8*)(inb + (size_t)row * 128 + c8);
    }
    *(short8*)&As[r * 136 + c8] = val;
  }
  __syncthreads();

  const int wave = t >> 6;
  const int lane = t & 63;
  const int m16 = lane & 15;
  const int quad = lane >> 4;
  const int rowA0 = wave * 32;  // wave covers 32 rows (2 row-tiles)

  floatx4 acc[2][CT];
#pragma unroll
  for (int rt = 0; rt < 2; ++rt)
#pragma unroll
    for (int ct = 0; ct < CT; ++ct) acc[rt][ct] = (floatx4){0.f, 0.f, 0.f, 0.f};

#pragma unroll
  for (int ks = 0; ks < 4; ++ks) {
    int koff = ks * 32 + quad * 8;
    short8 a0 = *(const short8*)&As[(rowA0 + m16) * 136 + koff];
    short8 a1 = *(const short8*)&As[(rowA0 + 16 + m16) * 136 + koff];
#pragma unroll
    for (int ct = 0; ct < CT; ++ct) {
      short8 b = *(const short8*)((const short*)Wt + (size_t)(ct * 16 + m16) * 128 + koff);
      acc[0][ct] = __builtin_amdgcn_mfma_f32_16x16x32_bf16(a0, b, acc[0][ct], 0, 0, 0);
      acc[1][ct] = __builtin_amdgcn_mfma_f32_16x16x32_bf16(a1, b, acc[1][ct], 0, 0, 0);
    }
  }

  float bv[CT];
  if (BIASRELU) {
#pragma unroll
    for (int ct = 0; ct < CT; ++ct) bv[ct] = bias[ct * 16 + m16];
  }
#pragma unroll
  for (int rt = 0; rt < 2; ++rt) {
    int rbase = row0 + rowA0 + rt * 16 + quad * 4;
#pragma unroll
    for (int reg = 0; reg < 4; ++reg) {
      int row = rbase + reg;
      if (row < M) {
        float mult = SCALE ? dinv[row] : 1.f;
#pragma unroll
        for (int ct = 0; ct < CT; ++ct) {
          float v = acc[rt][ct][reg];
          if (BIASRELU) v = fmaxf(v + bv[ct], 0.f);
          else v *= mult;
          out[(size_t)row * NC + ct * 16 + m16] = bf16_rn(v);
        }
      }
    }
  }
}

// ---------------- gather + dinv + bias + LayerNorm + ReLU (bf16 io) -------
// one wave per node; lane handles feature pair (2*lane, 2*lane+1)
__global__ __launch_bounds__(256) void aggregate_ln_kernel(
    const ushort_t* __restrict__ hs, const int* __restrict__ row_start,
    const int* __restrict__ srcs, const float* __restrict__ dinv,
    const float* __restrict__ bias, const float* __restrict__ gamma,
    const float* __restrict__ beta, ushort_t* __restrict__ out, int N) {
  int n = (blockIdx.x * 256 + threadIdx.x) >> 6;
  int lane = threadIdx.x & 63;
  if (n >= N) return;
  const uint_t* hsu = (const uint_t*)hs;  // 2 bf16 per uint, 64 per row
  size_t idx = (size_t)n * 64 + lane;
  uint_t sv = hsu[idx];
  float ax = bf16_lo(sv), ay = bf16_hi(sv);  // self loop term
  int beg = row_start[n], end = row_start[n + 1];
  int i = beg;
  for (; i + 4 <= end; i += 4) {
    int s0 = srcs[i], s1 = srcs[i + 1], s2 = srcs[i + 2], s3 = srcs[i + 3];
    uint_t v0 = hsu[(size_t)s0 * 64 + lane];
    uint_t v1 = hsu[(size_t)s1 * 64 + lane];
    uint_t v2 = hsu[(size_t)s2 * 64 + lane];
    uint_t v3 = hsu[(size_t)s3 * 64 + lane];
    ax += bf16_lo(v0) + bf16_lo(v1) + bf16_lo(v2) + bf16_lo(v3);
    ay += bf16_hi(v0) + bf16_hi(v1) + bf16_hi(v2) + bf16_hi(v3);
  }
  for (; i < end; ++i) {
    uint_t v = hsu[(size_t)srcs[i] * 64 + lane];
    ax += bf16_lo(v);
    ay += bf16_hi(v);
  }
  float dv = dinv[n];
  float2 bb = *(const float2*)(bias + 2 * lane);
  float yx = ax * dv + bb.x;
  float yy = ay * dv + bb.y;
  float s1 = yx + yy, s2v = yx * yx + yy * yy;
  for (int off = 32; off; off >>= 1) {
    s1 += __shfl_xor(s1, off);
    s2v += __shfl_xor(s2v, off);
  }
  float mu = s1 * (1.f / 128.f);
  float var = s2v * (1.f / 128.f) - mu * mu;
  float rinv = rsqrtf(var + 1e-5f);
  float2 gg = *(const float2*)(gamma + 2 * lane);
  float2 be = *(const float2*)(beta + 2 * lane);
  float o0 = fmaxf((yx - mu) * rinv * gg.x + be.x, 0.f);
  float o1 = fmaxf((yy - mu) * rinv * gg.y + be.y, 0.f);
  ((uint_t*)out)[idx] = bf16_pack(o0, o1);
}

// ---------------- gate = G @ Wg2 + bg2 (wave per node, G bf16) ------------
__global__ __launch_bounds__(256) void gate_dot_kernel(
    const ushort_t* __restrict__ G, const float* __restrict__ Wg2,
    const float* __restrict__ bg2, float* __restrict__ gate, int N) {
  int n = (blockIdx.x * 256 + threadIdx.x) >> 6;
  int lane = threadIdx.x & 63;
  if (n >= N) return;
  float g = __uint_as_float((uint_t)G[(size_t)n * 64 + lane] << 16);
  float v = g * Wg2[lane];
  for (int off = 32; off; off >>= 1) v += __shfl_xor(v, off);
  if (lane == 0) gate[n] = v + bg2[0];
}

// ---------------- segment softmax pool + classifier (h2 bf16) -------------
__device__ inline int lower_bound_i(const int* a, int n, int key) {
  int lo = 0, hi = n;
  while (lo < hi) {
    int mid = (lo + hi) >> 1;
    if (a[mid] < key) lo = mid + 1; else hi = mid;
  }
  return lo;
}

__global__ __launch_bounds__(256) void pool_kernel(
    const ushort_t* __restrict__ h2, const float* __restrict__ gate,
    const int* __restrict__ batch, const float* __restrict__ Wc,
    const float* __restrict__ bc, float* __restrict__ out, int N) {
  int g = blockIdx.x, t = threadIdx.x;
  __shared__ float redx[256];
  __shared__ float redy[256];
  __shared__ float pooled[128];
  __shared__ float s_gmax, s_inv;
  int lo = lower_bound_i(batch, N, g);
  int hi = lower_bound_i(batch, N, g + 1);
  // pass 1: max gate
  float m = -3.4e38f;
  for (int i = lo + t; i < hi; i += 256) m = fmaxf(m, gate[i]);
  redx[t] = m;
  __syncthreads();
  for (int off = 128; off; off >>= 1) {
    if (t < off) redx[t] = fmaxf(redx[t], redx[t + off]);
    __syncthreads();
  }
  if (t == 0) s_gmax = redx[0];
  __syncthreads();
  float gmax = s_gmax;
  __syncthreads();
  // pass 2: denom
  float ssum = 0.f;
  for (int i = lo + t; i < hi; i += 256) ssum += expf(gate[i] - gmax);
  redx[t] = ssum;
  __syncthreads();
  for (int off = 128; off; off >>= 1) {
    if (t < off) redx[t] += redx[t + off];
    __syncthreads();
  }
  if (t == 0) s_inv = redx[0] > 0.f ? 1.f / redx[0] : 0.f;
  __syncthreads();
  float inv = s_inv;
  __syncthreads();
  // pass 3: weighted feature sum; lane pair p covers features 2p,2p+1;
  // 4 node streams
  int p = t & 63, stream = t >> 6;
  const uint_t* h2u = (const uint_t*)h2;
  float accx = 0.f, accy = 0.f;
  int i = lo + stream;
  for (; i + 8 <= hi; i += 8) {
    float e0 = expf(gate[i] - gmax);
    float e1 = expf(gate[i + 4] - gmax);
    uint_t v0 = h2u[(size_t)i * 64 + p];
    uint_t v1 = h2u[(size_t)(i + 4) * 64 + p];
    accx += e0 * bf16_lo(v0) + e1 * bf16_lo(v1);
    accy += e0 * bf16_hi(v0) + e1 * bf16_hi(v1);
  }
  for (; i < hi; i += 4) {
    float e = expf(gate[i] - gmax);
    uint_t v = h2u[(size_t)i * 64 + p];
    accx += e * bf16_lo(v);
    accy += e * bf16_hi(v);
  }
  redx[t] = accx;
  redy[t] = accy;
  __syncthreads();
  if (t < 64) {
    float px = (redx[t] + redx[t + 64] + redx[t + 128] + redx[t + 192]) * inv;
    float py = (redy[t] + redy[t + 64] + redy[t + 128] + redy[t + 192]) * inv;
    pooled[2 * t] = px;
    pooled[2 * t + 1] = py;
  }
  __syncthreads();
  // classifier
  if (t < 16) {
    float o = bc[t];
    for (int ff = 0; ff < 128; ++ff) o = fmaf(pooled[ff], Wc[ff * 16 + t], o);
    out[g * 16 + t] = o;
  }
}

// ---------------- host launcher ----------------
extern "C" void kernel_launch(void* const* d_in, const int* in_sizes, int n_in,
                              void* d_out, int out_size, void* d_ws, size_t ws_size,
                              hipStream_t stream) {
  const float* x   = (const float*)d_in[0];
  const int*   ei  = (const int*)d_in[1];
  const int*   bat = (const int*)d_in[2];
  const float* W1  = (const float*)d_in[3];
  const float* b1  = (const float*)d_in[4];
  const float* g1  = (const float*)d_in[5];
  const float* be1 = (const float*)d_in[6];
  const float* W2  = (const float*)d_in[7];
  const float* b2  = (const float*)d_in[8];
  const float* g2  = (const float*)d_in[9];
  const float* be2 = (const float*)d_in[10];
  const float* Wg1 = (const float*)d_in[11];
  const float* bg1 = (const float*)d_in[12];
  const float* Wg2 = (const float*)d_in[13];
  const float* bg2 = (const float*)d_in[14];
  const float* Wc  = (const float*)d_in[15];
  const float* bc  = (const float*)d_in[16];

  const int N = in_sizes[0] / 128;
  const int E = in_sizes[1] / 2;
  const int B = out_size / 16;
  const int* src = ei;
  const int* dst = ei + E;

  const int Np = (N + 3) & ~3;
  const int Ep = (E + 3) & ~3;

  int* counts   = (int*)d_ws;            // Np (zeroed)
  int* fill     = counts + Np;           // Np (zeroed)
  int* rs       = fill + Np;             // Np + 4 (row_start, N+1 used)
  int* partials = rs + Np + 4;           // 128
  int* srcs     = partials + 128;        // Ep
  float* dinv   = (float*)(srcs + Ep);   // Np
  float* gatep  = dinv + Np;             // Np
  ushort_t* Wt  = (ushort_t*)(gatep + Np);  // 128*128 + 128*128 + 64*128 = 40960
  ushort_t* hs  = Wt + 40960;               // N*128 bf16 (also reused as G)
  ushort_t* h1  = hs + (size_t)128 * N;     // N*128 bf16 (h1, then h2)

  hipMemsetAsync(counts, 0, sizeof(int) * 2 * (size_t)Np, stream);

  const int nblk = (N + 1023) / 1024;
  count_edges_kernel<<<(E + 255) / 256, 256, 0, stream>>>(dst, counts, E);
  dinv_kernel<<<(N + 255) / 256, 256, 0, stream>>>(counts, dinv, N);
  scan_partials_kernel<<<nblk, 256, 0, stream>>>(counts, partials, N);
  scan_tops_kernel<<<1, 128, 0, stream>>>(partials, rs, nblk, N);
  scan_block_kernel<<<nblk, 256, 0, stream>>>(counts, partials, rs, N);
  place_edges_kernel<<<(E + 255) / 256, 256, 0, stream>>>(src, dst, rs, fill, srcs, E);
  prep_weights_kernel<<<320, 128, 0, stream>>>(W1, W2, Wg1, Wt);

  const int gblk = (N + 127) / 128;
  // conv1: hs = bf16((x@W1)*dinv)
  gemm_mfma_kernel<128, true, false, true><<<gblk, 256, 0, stream>>>(
      x, Wt, nullptr, dinv, hs, N);
  aggregate_ln_kernel<<<(N + 3) / 4, 256, 0, stream>>>(
      hs, rs, srcs, dinv, b1, g1, be1, h1, N);
  // conv2: hs2 (reuse hs) = bf16((h1@W2)*dinv); h2 overwrites h1
  gemm_mfma_kernel<128, true, false, false><<<gblk, 256, 0, stream>>>(
      h1, Wt + 16384, nullptr, dinv, hs, N);
  aggregate_ln_kernel<<<(N + 3) / 4, 256, 0, stream>>>(
      hs, rs, srcs, dinv, b2, g2, be2, h1, N);
  // gate MLP: G (reuse hs) = bf16(relu(h2@Wg1 + bg1))
  gemm_mfma_kernel<64, false, true, false><<<gblk, 256, 0, stream>>>(
      h1, Wt + 32768, bg1, nullptr, hs, N);
  gate_dot_kernel<<<(N + 3) / 4, 256, 0, stream>>>(hs, Wg2, bg2, gatep, N);
  // pool + classifier
  pool_kernel<<<B, 256, 0, stream>>>(h1, gatep, bat, Wc, bc, (float*)d_out, N);
}

// Round 3
// 536.545 us; speedup vs baseline: 1.6243x; 1.1883x over previous
//
#include <hip/hip_runtime.h>

// ---------------------------------------------------------------------------
// GCN pipeline (bf16 buffers, fp32 accumulation), R3:
//   K0  memset counts
//   K1  count+rank (atomicAdd returns rank[e])  ||  prep Wt (bf16 W^T)
//   K2-K4 scan chain (dinv fused into scan_block)
//   K5  place (no atomics, via rank)  ||  GEMM1 hs=bf16((x@W1)*dinv)   FUSED
//   K6  aggregate_ln1 -> h1
//   K7  GEMM2 hs2=bf16((h1@W2)*dinv)
//   K8  aggregate_ln2 -> h2
//   K9  gate GEMM + fused dot: gate = relu(h2@Wg1+bg1).Wg2+bg2 (G never stored)
//   K10 segment softmax pool + classifier
// ---------------------------------------------------------------------------

typedef unsigned short ushort_t;
typedef unsigned int uint_t;
typedef __attribute__((ext_vector_type(8))) short short8;   // 8 x bf16
typedef __attribute__((ext_vector_type(4))) float floatx4;  // MFMA acc

__device__ inline ushort_t bf16_rn(float f) {
  uint_t u = __float_as_uint(f);
  u += 0x7fffu + ((u >> 16) & 1u);
  return (ushort_t)(u >> 16);
}
__device__ inline float bf16_lo(uint_t v) { return __uint_as_float(v << 16); }
__device__ inline float bf16_hi(uint_t v) { return __uint_as_float(v & 0xffff0000u); }
__device__ inline uint_t bf16_pack(float a, float b) {
  return (uint_t)bf16_rn(a) | ((uint_t)bf16_rn(b) << 16);
}

// ---------------- K1: count+rank || weight prep ----------------
// blocks [0,160): transpose W1/W2/Wg1 into bf16 Wt ([n][k]); rest: count edges.
__global__ __launch_bounds__(256) void count_prep_kernel(
    const int* __restrict__ dst, int* __restrict__ counts,
    int* __restrict__ rank, int E,
    const float* __restrict__ W1, const float* __restrict__ W2,
    const float* __restrict__ Wg1, ushort_t* __restrict__ Wt) {
  int b = blockIdx.x, t = threadIdx.x;
  if (b < 160) {
    int id = b * 256 + t;  // [0, 40960)
    float v;
    if (id < 16384) {
      int n = id >> 7, k = id & 127;
      v = W1[k * 128 + n];
    } else if (id < 32768) {
      int i2 = id - 16384;
      int n = i2 >> 7, k = i2 & 127;
      v = W2[k * 128 + n];
    } else {
      int i2 = id - 32768;
      int n = i2 >> 7, k = i2 & 127;
      v = Wg1[k * 64 + n];
    }
    Wt[id] = bf16_rn(v);
  } else {
    int e = (b - 160) * 256 + t;
    if (e < E) rank[e] = atomicAdd(&counts[dst[e]], 1);
  }
}

// ---------------- scan chain ----------------
__global__ __launch_bounds__(256) void scan_partials_kernel(
    const int* __restrict__ counts, int* __restrict__ partials, int N) {
  __shared__ int s[256];
  int b = blockIdx.x, t = threadIdx.x;
  int base = b * 1024 + t * 4;
  int sum = 0;
  for (int i = 0; i < 4; ++i) {
    int idx = base + i;
    if (idx < N) sum += counts[idx];
  }
  s[t] = sum;
  __syncthreads();
  for (int off = 128; off; off >>= 1) {
    if (t < off) s[t] += s[t + off];
    __syncthreads();
  }
  if (t == 0) partials[b] = s[0];
}

__global__ __launch_bounds__(128) void scan_tops_kernel(
    int* __restrict__ partials, int* __restrict__ row_start, int nblk, int N) {
  __shared__ int s[128];
  int t = threadIdx.x;
  int v = t < nblk ? partials[t] : 0;
  s[t] = v;
  __syncthreads();
  for (int off = 1; off < 128; off <<= 1) {
    int x = (t >= off) ? s[t - off] : 0;
    __syncthreads();
    s[t] += x;
    __syncthreads();
  }
  if (t < nblk) partials[t] = s[t] - v;  // exclusive
  if (t == 127) row_start[N] = s[127];   // total == E
}

__global__ __launch_bounds__(256) void scan_block_kernel(
    const int* __restrict__ counts, const int* __restrict__ partials,
    int* __restrict__ row_start, float* __restrict__ dinv, int N) {
  __shared__ int s[256];
  int b = blockIdx.x, t = threadIdx.x;
  int base = b * 1024 + t * 4;
  int v[4];
  int sum = 0;
  for (int i = 0; i < 4; ++i) {
    int idx = base + i;
    v[i] = idx < N ? counts[idx] : 0;
    sum += v[i];
  }
  s[t] = sum;
  __syncthreads();
  for (int off = 1; off < 256; off <<= 1) {
    int x = (t >= off) ? s[t - off] : 0;
    __syncthreads();
    s[t] += x;
    __syncthreads();
  }
  int excl = s[t] - sum + partials[b];
  for (int i = 0; i < 4; ++i) {
    int idx = base + i;
    if (idx < N) {
      row_start[idx] = excl;
      dinv[idx] = rsqrtf((float)(v[i] + 1));  // +1 self loop
    }
    excl += v[i];
  }
}

// ---------------- K5: place (no atomics) || GEMM1 (fused roles) ----------
// grid = Gg*(K+1); r==0 -> GEMM block g, else place block g*K + r-1
__global__ __launch_bounds__(256) void gemm1_place_kernel(
    const float* __restrict__ x, const ushort_t* __restrict__ Wt,
    const float* __restrict__ dinv, ushort_t* __restrict__ hs, int M,
    const int* __restrict__ src, const int* __restrict__ dst,
    const int* __restrict__ row_start, const int* __restrict__ rank,
    int* __restrict__ srcs, int E, int K) {
  __shared__ short As[128 * 136];
  const int t = threadIdx.x;
  const int g = blockIdx.x / (K + 1);
  const int r = blockIdx.x % (K + 1);

  if (r != 0) {  // ---- place role ----
    int e = (g * K + r - 1) * 256 + t;
    if (e < E) {
      int d = dst[e];
      srcs[row_start[d] + rank[e]] = src[e];
    }
    return;
  }

  // ---- GEMM1 role: hs[row0..row0+128) = bf16((x@W1)*dinv) ----
  const int row0 = g * 128;
#pragma unroll
  for (int i = 0; i < 8; ++i) {
    int chunk = t + i * 256;
    int rr = chunk >> 4;
    int c8 = (chunk & 15) * 8;
    int row = row0 + rr;
    short8 val = {0, 0, 0, 0, 0, 0, 0, 0};
    if (row < M) {
      float4 v0 = *(const float4*)(x + (size_t)row * 128 + c8);
      float4 v1 = *(const float4*)(x + (size_t)row * 128 + c8 + 4);
      val[0] = (short)bf16_rn(v0.x); val[1] = (short)bf16_rn(v0.y);
      val[2] = (short)bf16_rn(v0.z); val[3] = (short)bf16_rn(v0.w);
      val[4] = (short)bf16_rn(v1.x); val[5] = (short)bf16_rn(v1.y);
      val[6] = (short)bf16_rn(v1.z); val[7] = (short)bf16_rn(v1.w);
    }
    *(short8*)&As[rr * 136 + c8] = val;
  }
  __syncthreads();

  const int wave = t >> 6, lane = t & 63;
  const int m16 = lane & 15, quad = lane >> 4;
  const int rowA0 = wave * 32;
  floatx4 acc[2][8];
#pragma unroll
  for (int rt = 0; rt < 2; ++rt)
#pragma unroll
    for (int ct = 0; ct < 8; ++ct) acc[rt][ct] = (floatx4){0.f, 0.f, 0.f, 0.f};
#pragma unroll
  for (int ks = 0; ks < 4; ++ks) {
    int koff = ks * 32 + quad * 8;
    short8 a0 = *(const short8*)&As[(rowA0 + m16) * 136 + koff];
    short8 a1 = *(const short8*)&As[(rowA0 + 16 + m16) * 136 + koff];
#pragma unroll
    for (int ct = 0; ct < 8; ++ct) {
      short8 b = *(const short8*)((const short*)Wt + (size_t)(ct * 16 + m16) * 128 + koff);
      acc[0][ct] = __builtin_amdgcn_mfma_f32_16x16x32_bf16(a0, b, acc[0][ct], 0, 0, 0);
      acc[1][ct] = __builtin_amdgcn_mfma_f32_16x16x32_bf16(a1, b, acc[1][ct], 0, 0, 0);
    }
  }
#pragma unroll
  for (int rt = 0; rt < 2; ++rt) {
    int rbase = row0 + rowA0 + rt * 16 + quad * 4;
#pragma unroll
    for (int reg = 0; reg < 4; ++reg) {
      int row = rbase + reg;
      if (row < M) {
        float mult = dinv[row];
#pragma unroll
        for (int ct = 0; ct < 8; ++ct)
          hs[(size_t)row * 128 + ct * 16 + m16] = bf16_rn(acc[rt][ct][reg] * mult);
      }
    }
  }
}

// ---------------- MFMA GEMM template (GEMM2 + gate GEMM w/ fused dot) -----
template <int NC, bool SCALE, bool BIASRELU, bool GATEDOT>
__global__ __launch_bounds__(256) void gemm_mfma_kernel(
    const ushort_t* __restrict__ in, const ushort_t* __restrict__ Wt,
    const float* __restrict__ bias, const float* __restrict__ dinv,
    ushort_t* __restrict__ out, int M,
    const float* __restrict__ Wg2, const float* __restrict__ bg2,
    float* __restrict__ gate_out) {
  constexpr int CT = NC / 16;
  __shared__ short As[128 * 136];
  const int t = threadIdx.x;
  const int row0 = blockIdx.x * 128;

#pragma unroll
  for (int i = 0; i < 8; ++i) {
    int chunk = t + i * 256;
    int rr = chunk >> 4;
    int c8 = (chunk & 15) * 8;
    int row = row0 + rr;
    short8 val = {0, 0, 0, 0, 0, 0, 0, 0};
    if (row < M) val = *(const short8*)((const short*)in + (size_t)row * 128 + c8);
    *(short8*)&As[rr * 136 + c8] = val;
  }
  __syncthreads();

  const int wave = t >> 6, lane = t & 63;
  const int m16 = lane & 15, quad = lane >> 4;
  const int rowA0 = wave * 32;
  floatx4 acc[2][CT];
#pragma unroll
  for (int rt = 0; rt < 2; ++rt)
#pragma unroll
    for (int ct = 0; ct < CT; ++ct) acc[rt][ct] = (floatx4){0.f, 0.f, 0.f, 0.f};
#pragma unroll
  for (int ks = 0; ks < 4; ++ks) {
    int koff = ks * 32 + quad * 8;
    short8 a0 = *(const short8*)&As[(rowA0 + m16) * 136 + koff];
    short8 a1 = *(const short8*)&As[(rowA0 + 16 + m16) * 136 + koff];
#pragma unroll
    for (int ct = 0; ct < CT; ++ct) {
      short8 b = *(const short8*)((const short*)Wt + (size_t)(ct * 16 + m16) * 128 + koff);
      acc[0][ct] = __builtin_amdgcn_mfma_f32_16x16x32_bf16(a0, b, acc[0][ct], 0, 0, 0);
      acc[1][ct] = __builtin_amdgcn_mfma_f32_16x16x32_bf16(a1, b, acc[1][ct], 0, 0, 0);
    }
  }

  float bv[CT];
  if (BIASRELU) {
#pragma unroll
    for (int ct = 0; ct < CT; ++ct) bv[ct] = bias[ct * 16 + m16];
  }

  if (GATEDOT) {
    float w2[CT];
#pragma unroll
    for (int ct = 0; ct < CT; ++ct) w2[ct] = Wg2[ct * 16 + m16];
    float bg2v = bg2[0];
#pragma unroll
    for (int rt = 0; rt < 2; ++rt) {
#pragma unroll
      for (int reg = 0; reg < 4; ++reg) {
        float p = 0.f;
#pragma unroll
        for (int ct = 0; ct < CT; ++ct)
          p += fmaxf(acc[rt][ct][reg] + bv[ct], 0.f) * w2[ct];
        p += __shfl_xor(p, 1);
        p += __shfl_xor(p, 2);
        p += __shfl_xor(p, 4);
        p += __shfl_xor(p, 8);
        if (m16 == 0) {
          int row = row0 + rowA0 + rt * 16 + quad * 4 + reg;
          if (row < M) gate_out[row] = p + bg2v;
        }
      }
    }
    return;
  }

#pragma unroll
  for (int rt = 0; rt < 2; ++rt) {
    int rbase = row0 + rowA0 + rt * 16 + quad * 4;
#pragma unroll
    for (int reg = 0; reg < 4; ++reg) {
      int row = rbase + reg;
      if (row < M) {
        float mult = SCALE ? dinv[row] : 1.f;
#pragma unroll
        for (int ct = 0; ct < CT; ++ct) {
          float v = acc[rt][ct][reg];
          if (BIASRELU) v = fmaxf(v + bv[ct], 0.f);
          else v *= mult;
          out[(size_t)row * NC + ct * 16 + m16] = bf16_rn(v);
        }
      }
    }
  }
}

// ---------------- gather + dinv + bias + LayerNorm + ReLU (bf16 io) -------
__global__ __launch_bounds__(256) void aggregate_ln_kernel(
    const ushort_t* __restrict__ hs, const int* __restrict__ row_start,
    const int* __restrict__ srcs, const float* __restrict__ dinv,
    const float* __restrict__ bias, const float* __restrict__ gamma,
    const float* __restrict__ beta, ushort_t* __restrict__ out, int N) {
  int n = (blockIdx.x * 256 + threadIdx.x) >> 6;
  int lane = threadIdx.x & 63;
  if (n >= N) return;
  const uint_t* hsu = (const uint_t*)hs;
  size_t idx = (size_t)n * 64 + lane;
  uint_t sv = hsu[idx];
  float ax = bf16_lo(sv), ay = bf16_hi(sv);  // self loop
  int beg = row_start[n], end = row_start[n + 1];
  int i = beg;
  for (; i + 8 <= end; i += 8) {
    int s0 = srcs[i], s1 = srcs[i + 1], s2 = srcs[i + 2], s3 = srcs[i + 3];
    int s4 = srcs[i + 4], s5 = srcs[i + 5], s6 = srcs[i + 6], s7 = srcs[i + 7];
    uint_t v0 = hsu[(size_t)s0 * 64 + lane];
    uint_t v1 = hsu[(size_t)s1 * 64 + lane];
    uint_t v2 = hsu[(size_t)s2 * 64 + lane];
    uint_t v3 = hsu[(size_t)s3 * 64 + lane];
    uint_t v4 = hsu[(size_t)s4 * 64 + lane];
    uint_t v5 = hsu[(size_t)s5 * 64 + lane];
    uint_t v6 = hsu[(size_t)s6 * 64 + lane];
    uint_t v7 = hsu[(size_t)s7 * 64 + lane];
    ax += bf16_lo(v0) + bf16_lo(v1) + bf16_lo(v2) + bf16_lo(v3) +
          bf16_lo(v4) + bf16_lo(v5) + bf16_lo(v6) + bf16_lo(v7);
    ay += bf16_hi(v0) + bf16_hi(v1) + bf16_hi(v2) + bf16_hi(v3) +
          bf16_hi(v4) + bf16_hi(v5) + bf16_hi(v6) + bf16_hi(v7);
  }
  for (; i + 4 <= end; i += 4) {
    int s0 = srcs[i], s1 = srcs[i + 1], s2 = srcs[i + 2], s3 = srcs[i + 3];
    uint_t v0 = hsu[(size_t)s0 * 64 + lane];
    uint_t v1 = hsu[(size_t)s1 * 64 + lane];
    uint_t v2 = hsu[(size_t)s2 * 64 + lane];
    uint_t v3 = hsu[(size_t)s3 * 64 + lane];
    ax += bf16_lo(v0) + bf16_lo(v1) + bf16_lo(v2) + bf16_lo(v3);
    ay += bf16_hi(v0) + bf16_hi(v1) + bf16_hi(v2) + bf16_hi(v3);
  }
  for (; i < end; ++i) {
    uint_t v = hsu[(size_t)srcs[i] * 64 + lane];
    ax += bf16_lo(v);
    ay += bf16_hi(v);
  }
  float dv = dinv[n];
  float2 bb = *(const float2*)(bias + 2 * lane);
  float yx = ax * dv + bb.x;
  float yy = ay * dv + bb.y;
  float s1 = yx + yy, s2v = yx * yx + yy * yy;
  for (int off = 32; off; off >>= 1) {
    s1 += __shfl_xor(s1, off);
    s2v += __shfl_xor(s2v, off);
  }
  float mu = s1 * (1.f / 128.f);
  float var = s2v * (1.f / 128.f) - mu * mu;
  float rinv = rsqrtf(var + 1e-5f);
  float2 gg = *(const float2*)(gamma + 2 * lane);
  float2 be = *(const float2*)(beta + 2 * lane);
  float o0 = fmaxf((yx - mu) * rinv * gg.x + be.x, 0.f);
  float o1 = fmaxf((yy - mu) * rinv * gg.y + be.y, 0.f);
  ((uint_t*)out)[idx] = bf16_pack(o0, o1);
}

// ---------------- segment softmax pool + classifier (h2 bf16) -------------
__device__ inline int lower_bound_i(const int* a, int n, int key) {
  int lo = 0, hi = n;
  while (lo < hi) {
    int mid = (lo + hi) >> 1;
    if (a[mid] < key) lo = mid + 1; else hi = mid;
  }
  return lo;
}

__global__ __launch_bounds__(256) void pool_kernel(
    const ushort_t* __restrict__ h2, const float* __restrict__ gate,
    const int* __restrict__ batch, const float* __restrict__ Wc,
    const float* __restrict__ bc, float* __restrict__ out, int N) {
  int g = blockIdx.x, t = threadIdx.x;
  __shared__ float redx[256];
  __shared__ float redy[256];
  __shared__ float pooled[128];
  __shared__ float s_gmax, s_inv;
  int lo = lower_bound_i(batch, N, g);
  int hi = lower_bound_i(batch, N, g + 1);
  float m = -3.4e38f;
  for (int i = lo + t; i < hi; i += 256) m = fmaxf(m, gate[i]);
  redx[t] = m;
  __syncthreads();
  for (int off = 128; off; off >>= 1) {
    if (t < off) redx[t] = fmaxf(redx[t], redx[t + off]);
    __syncthreads();
  }
  if (t == 0) s_gmax = redx[0];
  __syncthreads();
  float gmax = s_gmax;
  __syncthreads();
  float ssum = 0.f;
  for (int i = lo + t; i < hi; i += 256) ssum += expf(gate[i] - gmax);
  redx[t] = ssum;
  __syncthreads();
  for (int off = 128; off; off >>= 1) {
    if (t < off) redx[t] += redx[t + off];
    __syncthreads();
  }
  if (t == 0) s_inv = redx[0] > 0.f ? 1.f / redx[0] : 0.f;
  __syncthreads();
  float inv = s_inv;
  __syncthreads();
  int p = t & 63, strm = t >> 6;
  const uint_t* h2u = (const uint_t*)h2;
  float accx = 0.f, accy = 0.f;
  int i = lo + strm;
  for (; i + 8 <= hi; i += 8) {
    float e0 = expf(gate[i] - gmax);
    float e1 = expf(gate[i + 4] - gmax);
    uint_t v0 = h2u[(size_t)i * 64 + p];
    uint_t v1 = h2u[(size_t)(i + 4) * 64 + p];
    accx += e0 * bf16_lo(v0) + e1 * bf16_lo(v1);
    accy += e0 * bf16_hi(v0) + e1 * bf16_hi(v1);
  }
  for (; i < hi; i += 4) {
    float e = expf(gate[i] - gmax);
    uint_t v = h2u[(size_t)i * 64 + p];
    accx += e * bf16_lo(v);
    accy += e * bf16_hi(v);
  }
  redx[t] = accx;
  redy[t] = accy;
  __syncthreads();
  if (t < 64) {
    pooled[2 * t]     = (redx[t] + redx[t + 64] + redx[t + 128] + redx[t + 192]) * inv;
    pooled[2 * t + 1] = (redy[t] + redy[t + 64] + redy[t + 128] + redy[t + 192]) * inv;
  }
  __syncthreads();
  if (t < 16) {
    float o = bc[t];
    for (int ff = 0; ff < 128; ++ff) o = fmaf(pooled[ff], Wc[ff * 16 + t], o);
    out[g * 16 + t] = o;
  }
}

// ---------------- host launcher ----------------
extern "C" void kernel_launch(void* const* d_in, const int* in_sizes, int n_in,
                              void* d_out, int out_size, void* d_ws, size_t ws_size,
                              hipStream_t stream) {
  const float* x   = (const float*)d_in[0];
  const int*   ei  = (const int*)d_in[1];
  const int*   bat = (const int*)d_in[2];
  const float* W1  = (const float*)d_in[3];
  const float* b1  = (const float*)d_in[4];
  const float* g1  = (const float*)d_in[5];
  const float* be1 = (const float*)d_in[6];
  const float* W2  = (const float*)d_in[7];
  const float* b2  = (const float*)d_in[8];
  const float* g2  = (const float*)d_in[9];
  const float* be2 = (const float*)d_in[10];
  const float* Wg1 = (const float*)d_in[11];
  const float* bg1 = (const float*)d_in[12];
  const float* Wg2 = (const float*)d_in[13];
  const float* bg2 = (const float*)d_in[14];
  const float* Wc  = (const float*)d_in[15];
  const float* bc  = (const float*)d_in[16];

  const int N = in_sizes[0] / 128;
  const int E = in_sizes[1] / 2;
  const int B = out_size / 16;
  const int* src = ei;
  const int* dst = ei + E;

  const int Np = (N + 3) & ~3;
  const int Ep = (E + 3) & ~3;

  int* counts   = (int*)d_ws;               // Np (zeroed)
  int* rank     = counts + Np;              // Ep
  int* rs       = rank + Ep;                // Np + 4
  int* partials = rs + Np + 4;              // 128
  int* srcs     = partials + 128;           // Ep
  float* dinv   = (float*)(srcs + Ep);      // Np
  float* gatep  = dinv + Np;                // Np
  ushort_t* Wt  = (ushort_t*)(gatep + Np);  // 40960
  ushort_t* hs  = Wt + 40960;               // N*128 bf16
  ushort_t* h1  = hs + (size_t)128 * N;     // N*128 bf16 (h1, then h2)

  hipMemsetAsync(counts, 0, sizeof(int) * (size_t)Np, stream);

  const int nblk = (N + 1023) / 1024;
  const int cblk = (E + 255) / 256;
  count_prep_kernel<<<160 + cblk, 256, 0, stream>>>(dst, counts, rank, E, W1, W2, Wg1, Wt);
  scan_partials_kernel<<<nblk, 256, 0, stream>>>(counts, partials, N);
  scan_tops_kernel<<<1, 128, 0, stream>>>(partials, rs, nblk, N);
  scan_block_kernel<<<nblk, 256, 0, stream>>>(counts, partials, rs, dinv, N);

  // fused: place || GEMM1
  const int Gg = (N + 127) / 128;
  const int Gp = (E + 255) / 256;
  const int K = (Gp + Gg - 1) / Gg;
  gemm1_place_kernel<<<Gg * (K + 1), 256, 0, stream>>>(
      x, Wt, dinv, hs, N, src, dst, rs, rank, srcs, E, K);

  aggregate_ln_kernel<<<(N + 3) / 4, 256, 0, stream>>>(
      hs, rs, srcs, dinv, b1, g1, be1, h1, N);
  gemm_mfma_kernel<128, true, false, false><<<Gg, 256, 0, stream>>>(
      h1, Wt + 16384, nullptr, dinv, hs, N, nullptr, nullptr, nullptr);
  aggregate_ln_kernel<<<(N + 3) / 4, 256, 0, stream>>>(
      hs, rs, srcs, dinv, b2, g2, be2, h1, N);
  // gate GEMM with fused dot -> gate[N]
  gemm_mfma_kernel<64, false, true, true><<<Gg, 256, 0, stream>>>(
      h1, Wt + 32768, bg1, nullptr, nullptr, N, Wg2, bg2, gatep);
  pool_kernel<<<B, 256, 0, stream>>>(h1, gatep, bat, Wc, bc, (float*)d_out, N);
}

// Round 4
// 486.131 us; speedup vs baseline: 1.7927x; 1.1037x over previous
//
#include <hip/hip_runtime.h>

// ---------------------------------------------------------------------------
// GCN pipeline (bf16 buffers, fp32 accumulation), R4:
//   K0  memset counts
//   K1  count+rank (atomicAdd returns rank[e])  ||  prep Wt (bf16 W^T)
//   K2-K4 scan chain (dinv fused into scan_block)
//   K5  place (no atomics, via rank)  ||  GEMM1 hs=bf16((x@W1)*dinv)   FUSED
//   K6  aggregate_ln1 -> h1
//   K7  GEMM2 hs2=bf16((h1@W2)*dinv)
//   K8  aggregate_ln2 -> h2
//   K9  gate GEMM + fused dot: gate = relu(h2@Wg1+bg1).Wg2+bg2 (G never stored)
//   K10 gate_stats (grid B): gmax, 1/denom per graph
//   K11 pool_partial (grid B*16): weighted partial sums -> partial[B][16][128]
//   K12 classify (grid B): reduce partials, @Wc + bc -> out
// ---------------------------------------------------------------------------

typedef unsigned short ushort_t;
typedef unsigned int uint_t;
typedef __attribute__((ext_vector_type(8))) short short8;   // 8 x bf16
typedef __attribute__((ext_vector_type(4))) float floatx4;  // MFMA acc

#define POOL_S 16  // sub-blocks per graph in pool_partial

__device__ inline ushort_t bf16_rn(float f) {
  uint_t u = __float_as_uint(f);
  u += 0x7fffu + ((u >> 16) & 1u);
  return (ushort_t)(u >> 16);
}
__device__ inline float bf16_lo(uint_t v) { return __uint_as_float(v << 16); }
__device__ inline float bf16_hi(uint_t v) { return __uint_as_float(v & 0xffff0000u); }
__device__ inline uint_t bf16_pack(float a, float b) {
  return (uint_t)bf16_rn(a) | ((uint_t)bf16_rn(b) << 16);
}

// ---------------- K1: count+rank || weight prep ----------------
__global__ __launch_bounds__(256) void count_prep_kernel(
    const int* __restrict__ dst, int* __restrict__ counts,
    int* __restrict__ rank, int E,
    const float* __restrict__ W1, const float* __restrict__ W2,
    const float* __restrict__ Wg1, ushort_t* __restrict__ Wt) {
  int b = blockIdx.x, t = threadIdx.x;
  if (b < 160) {
    int id = b * 256 + t;  // [0, 40960)
    float v;
    if (id < 16384) {
      int n = id >> 7, k = id & 127;
      v = W1[k * 128 + n];
    } else if (id < 32768) {
      int i2 = id - 16384;
      int n = i2 >> 7, k = i2 & 127;
      v = W2[k * 128 + n];
    } else {
      int i2 = id - 32768;
      int n = i2 >> 7, k = i2 & 127;
      v = Wg1[k * 64 + n];
    }
    Wt[id] = bf16_rn(v);
  } else {
    int e = (b - 160) * 256 + t;
    if (e < E) rank[e] = atomicAdd(&counts[dst[e]], 1);
  }
}

// ---------------- scan chain ----------------
__global__ __launch_bounds__(256) void scan_partials_kernel(
    const int* __restrict__ counts, int* __restrict__ partials, int N) {
  __shared__ int s[256];
  int b = blockIdx.x, t = threadIdx.x;
  int base = b * 1024 + t * 4;
  int sum = 0;
  for (int i = 0; i < 4; ++i) {
    int idx = base + i;
    if (idx < N) sum += counts[idx];
  }
  s[t] = sum;
  __syncthreads();
  for (int off = 128; off; off >>= 1) {
    if (t < off) s[t] += s[t + off];
    __syncthreads();
  }
  if (t == 0) partials[b] = s[0];
}

__global__ __launch_bounds__(128) void scan_tops_kernel(
    int* __restrict__ partials, int* __restrict__ row_start, int nblk, int N) {
  __shared__ int s[128];
  int t = threadIdx.x;
  int v = t < nblk ? partials[t] : 0;
  s[t] = v;
  __syncthreads();
  for (int off = 1; off < 128; off <<= 1) {
    int x = (t >= off) ? s[t - off] : 0;
    __syncthreads();
    s[t] += x;
    __syncthreads();
  }
  if (t < nblk) partials[t] = s[t] - v;  // exclusive
  if (t == 127) row_start[N] = s[127];   // total == E
}

__global__ __launch_bounds__(256) void scan_block_kernel(
    const int* __restrict__ counts, const int* __restrict__ partials,
    int* __restrict__ row_start, float* __restrict__ dinv, int N) {
  __shared__ int s[256];
  int b = blockIdx.x, t = threadIdx.x;
  int base = b * 1024 + t * 4;
  int v[4];
  int sum = 0;
  for (int i = 0; i < 4; ++i) {
    int idx = base + i;
    v[i] = idx < N ? counts[idx] : 0;
    sum += v[i];
  }
  s[t] = sum;
  __syncthreads();
  for (int off = 1; off < 256; off <<= 1) {
    int x = (t >= off) ? s[t - off] : 0;
    __syncthreads();
    s[t] += x;
    __syncthreads();
  }
  int excl = s[t] - sum + partials[b];
  for (int i = 0; i < 4; ++i) {
    int idx = base + i;
    if (idx < N) {
      row_start[idx] = excl;
      dinv[idx] = rsqrtf((float)(v[i] + 1));  // +1 self loop
    }
    excl += v[i];
  }
}

// ---------------- K5: place (no atomics) || GEMM1 (fused roles) ----------
__global__ __launch_bounds__(256) void gemm1_place_kernel(
    const float* __restrict__ x, const ushort_t* __restrict__ Wt,
    const float* __restrict__ dinv, ushort_t* __restrict__ hs, int M,
    const int* __restrict__ src, const int* __restrict__ dst,
    const int* __restrict__ row_start, const int* __restrict__ rank,
    int* __restrict__ srcs, int E, int K) {
  __shared__ short As[128 * 136];
  const int t = threadIdx.x;
  const int g = blockIdx.x / (K + 1);
  const int r = blockIdx.x % (K + 1);

  if (r != 0) {  // ---- place role ----
    int e = (g * K + r - 1) * 256 + t;
    if (e < E) {
      int d = dst[e];
      srcs[row_start[d] + rank[e]] = src[e];
    }
    return;
  }

  // ---- GEMM1 role ----
  const int row0 = g * 128;
#pragma unroll
  for (int i = 0; i < 8; ++i) {
    int chunk = t + i * 256;
    int rr = chunk >> 4;
    int c8 = (chunk & 15) * 8;
    int row = row0 + rr;
    short8 val = {0, 0, 0, 0, 0, 0, 0, 0};
    if (row < M) {
      float4 v0 = *(const float4*)(x + (size_t)row * 128 + c8);
      float4 v1 = *(const float4*)(x + (size_t)row * 128 + c8 + 4);
      val[0] = (short)bf16_rn(v0.x); val[1] = (short)bf16_rn(v0.y);
      val[2] = (short)bf16_rn(v0.z); val[3] = (short)bf16_rn(v0.w);
      val[4] = (short)bf16_rn(v1.x); val[5] = (short)bf16_rn(v1.y);
      val[6] = (short)bf16_rn(v1.z); val[7] = (short)bf16_rn(v1.w);
    }
    *(short8*)&As[rr * 136 + c8] = val;
  }
  __syncthreads();

  const int wave = t >> 6, lane = t & 63;
  const int m16 = lane & 15, quad = lane >> 4;
  const int rowA0 = wave * 32;
  floatx4 acc[2][8];
#pragma unroll
  for (int rt = 0; rt < 2; ++rt)
#pragma unroll
    for (int ct = 0; ct < 8; ++ct) acc[rt][ct] = (floatx4){0.f, 0.f, 0.f, 0.f};
#pragma unroll
  for (int ks = 0; ks < 4; ++ks) {
    int koff = ks * 32 + quad * 8;
    short8 a0 = *(const short8*)&As[(rowA0 + m16) * 136 + koff];
    short8 a1 = *(const short8*)&As[(rowA0 + 16 + m16) * 136 + koff];
#pragma unroll
    for (int ct = 0; ct < 8; ++ct) {
      short8 b = *(const short8*)((const short*)Wt + (size_t)(ct * 16 + m16) * 128 + koff);
      acc[0][ct] = __builtin_amdgcn_mfma_f32_16x16x32_bf16(a0, b, acc[0][ct], 0, 0, 0);
      acc[1][ct] = __builtin_amdgcn_mfma_f32_16x16x32_bf16(a1, b, acc[1][ct], 0, 0, 0);
    }
  }
#pragma unroll
  for (int rt = 0; rt < 2; ++rt) {
    int rbase = row0 + rowA0 + rt * 16 + quad * 4;
#pragma unroll
    for (int reg = 0; reg < 4; ++reg) {
      int row = rbase + reg;
      if (row < M) {
        float mult = dinv[row];
#pragma unroll
        for (int ct = 0; ct < 8; ++ct)
          hs[(size_t)row * 128 + ct * 16 + m16] = bf16_rn(acc[rt][ct][reg] * mult);
      }
    }
  }
}

// ---------------- MFMA GEMM template (GEMM2 + gate GEMM w/ fused dot) -----
template <int NC, bool SCALE, bool BIASRELU, bool GATEDOT>
__global__ __launch_bounds__(256) void gemm_mfma_kernel(
    const ushort_t* __restrict__ in, const ushort_t* __restrict__ Wt,
    const float* __restrict__ bias, const float* __restrict__ dinv,
    ushort_t* __restrict__ out, int M,
    const float* __restrict__ Wg2, const float* __restrict__ bg2,
    float* __restrict__ gate_out) {
  constexpr int CT = NC / 16;
  __shared__ short As[128 * 136];
  const int t = threadIdx.x;
  const int row0 = blockIdx.x * 128;

#pragma unroll
  for (int i = 0; i < 8; ++i) {
    int chunk = t + i * 256;
    int rr = chunk >> 4;
    int c8 = (chunk & 15) * 8;
    int row = row0 + rr;
    short8 val = {0, 0, 0, 0, 0, 0, 0, 0};
    if (row < M) val = *(const short8*)((const short*)in + (size_t)row * 128 + c8);
    *(short8*)&As[rr * 136 + c8] = val;
  }
  __syncthreads();

  const int wave = t >> 6, lane = t & 63;
  const int m16 = lane & 15, quad = lane >> 4;
  const int rowA0 = wave * 32;
  floatx4 acc[2][CT];
#pragma unroll
  for (int rt = 0; rt < 2; ++rt)
#pragma unroll
    for (int ct = 0; ct < CT; ++ct) acc[rt][ct] = (floatx4){0.f, 0.f, 0.f, 0.f};
#pragma unroll
  for (int ks = 0; ks < 4; ++ks) {
    int koff = ks * 32 + quad * 8;
    short8 a0 = *(const short8*)&As[(rowA0 + m16) * 136 + koff];
    short8 a1 = *(const short8*)&As[(rowA0 + 16 + m16) * 136 + koff];
#pragma unroll
    for (int ct = 0; ct < CT; ++ct) {
      short8 b = *(const short8*)((const short*)Wt + (size_t)(ct * 16 + m16) * 128 + koff);
      acc[0][ct] = __builtin_amdgcn_mfma_f32_16x16x32_bf16(a0, b, acc[0][ct], 0, 0, 0);
      acc[1][ct] = __builtin_amdgcn_mfma_f32_16x16x32_bf16(a1, b, acc[1][ct], 0, 0, 0);
    }
  }

  float bv[CT];
  if (BIASRELU) {
#pragma unroll
    for (int ct = 0; ct < CT; ++ct) bv[ct] = bias[ct * 16 + m16];
  }

  if (GATEDOT) {
    float w2[CT];
#pragma unroll
    for (int ct = 0; ct < CT; ++ct) w2[ct] = Wg2[ct * 16 + m16];
    float bg2v = bg2[0];
#pragma unroll
    for (int rt = 0; rt < 2; ++rt) {
#pragma unroll
      for (int reg = 0; reg < 4; ++reg) {
        float p = 0.f;
#pragma unroll
        for (int ct = 0; ct < CT; ++ct)
          p += fmaxf(acc[rt][ct][reg] + bv[ct], 0.f) * w2[ct];
        p += __shfl_xor(p, 1);
        p += __shfl_xor(p, 2);
        p += __shfl_xor(p, 4);
        p += __shfl_xor(p, 8);
        if (m16 == 0) {
          int row = row0 + rowA0 + rt * 16 + quad * 4 + reg;
          if (row < M) gate_out[row] = p + bg2v;
        }
      }
    }
    return;
  }

#pragma unroll
  for (int rt = 0; rt < 2; ++rt) {
    int rbase = row0 + rowA0 + rt * 16 + quad * 4;
#pragma unroll
    for (int reg = 0; reg < 4; ++reg) {
      int row = rbase + reg;
      if (row < M) {
        float mult = SCALE ? dinv[row] : 1.f;
#pragma unroll
        for (int ct = 0; ct < CT; ++ct) {
          float v = acc[rt][ct][reg];
          if (BIASRELU) v = fmaxf(v + bv[ct], 0.f);
          else v *= mult;
          out[(size_t)row * NC + ct * 16 + m16] = bf16_rn(v);
        }
      }
    }
  }
}

// ---------------- gather + dinv + bias + LayerNorm + ReLU (bf16 io) -------
__global__ __launch_bounds__(256) void aggregate_ln_kernel(
    const ushort_t* __restrict__ hs, const int* __restrict__ row_start,
    const int* __restrict__ srcs, const float* __restrict__ dinv,
    const float* __restrict__ bias, const float* __restrict__ gamma,
    const float* __restrict__ beta, ushort_t* __restrict__ out, int N) {
  int n = (blockIdx.x * 256 + threadIdx.x) >> 6;
  int lane = threadIdx.x & 63;
  if (n >= N) return;
  const uint_t* hsu = (const uint_t*)hs;
  size_t idx = (size_t)n * 64 + lane;
  uint_t sv = hsu[idx];
  float ax = bf16_lo(sv), ay = bf16_hi(sv);  // self loop
  int beg = row_start[n], end = row_start[n + 1];
  int i = beg;
  for (; i + 8 <= end; i += 8) {
    int s0 = srcs[i], s1 = srcs[i + 1], s2 = srcs[i + 2], s3 = srcs[i + 3];
    int s4 = srcs[i + 4], s5 = srcs[i + 5], s6 = srcs[i + 6], s7 = srcs[i + 7];
    uint_t v0 = hsu[(size_t)s0 * 64 + lane];
    uint_t v1 = hsu[(size_t)s1 * 64 + lane];
    uint_t v2 = hsu[(size_t)s2 * 64 + lane];
    uint_t v3 = hsu[(size_t)s3 * 64 + lane];
    uint_t v4 = hsu[(size_t)s4 * 64 + lane];
    uint_t v5 = hsu[(size_t)s5 * 64 + lane];
    uint_t v6 = hsu[(size_t)s6 * 64 + lane];
    uint_t v7 = hsu[(size_t)s7 * 64 + lane];
    ax += bf16_lo(v0) + bf16_lo(v1) + bf16_lo(v2) + bf16_lo(v3) +
          bf16_lo(v4) + bf16_lo(v5) + bf16_lo(v6) + bf16_lo(v7);
    ay += bf16_hi(v0) + bf16_hi(v1) + bf16_hi(v2) + bf16_hi(v3) +
          bf16_hi(v4) + bf16_hi(v5) + bf16_hi(v6) + bf16_hi(v7);
  }
  for (; i + 4 <= end; i += 4) {
    int s0 = srcs[i], s1 = srcs[i + 1], s2 = srcs[i + 2], s3 = srcs[i + 3];
    uint_t v0 = hsu[(size_t)s0 * 64 + lane];
    uint_t v1 = hsu[(size_t)s1 * 64 + lane];
    uint_t v2 = hsu[(size_t)s2 * 64 + lane];
    uint_t v3 = hsu[(size_t)s3 * 64 + lane];
    ax += bf16_lo(v0) + bf16_lo(v1) + bf16_lo(v2) + bf16_lo(v3);
    ay += bf16_hi(v0) + bf16_hi(v1) + bf16_hi(v2) + bf16_hi(v3);
  }
  for (; i < end; ++i) {
    uint_t v = hsu[(size_t)srcs[i] * 64 + lane];
    ax += bf16_lo(v);
    ay += bf16_hi(v);
  }
  float dv = dinv[n];
  float2 bb = *(const float2*)(bias + 2 * lane);
  float yx = ax * dv + bb.x;
  float yy = ay * dv + bb.y;
  float s1 = yx + yy, s2v = yx * yx + yy * yy;
  for (int off = 32; off; off >>= 1) {
    s1 += __shfl_xor(s1, off);
    s2v += __shfl_xor(s2v, off);
  }
  float mu = s1 * (1.f / 128.f);
  float var = s2v * (1.f / 128.f) - mu * mu;
  float rinv = rsqrtf(var + 1e-5f);
  float2 gg = *(const float2*)(gamma + 2 * lane);
  float2 be = *(const float2*)(beta + 2 * lane);
  float o0 = fmaxf((yx - mu) * rinv * gg.x + be.x, 0.f);
  float o1 = fmaxf((yy - mu) * rinv * gg.y + be.y, 0.f);
  ((uint_t*)out)[idx] = bf16_pack(o0, o1);
}

// ---------------- segment softmax pooling, split across 3 kernels ---------
__device__ inline int lower_bound_i(const int* a, int n, int key) {
  int lo = 0, hi = n;
  while (lo < hi) {
    int mid = (lo + hi) >> 1;
    if (a[mid] < key) lo = mid + 1; else hi = mid;
  }
  return lo;
}

// K10: per-graph gate max and 1/sum(exp)
__global__ __launch_bounds__(256) void gate_stats_kernel(
    const float* __restrict__ gate, const int* __restrict__ batch,
    float* __restrict__ gmax_out, float* __restrict__ ginv_out, int N) {
  int g = blockIdx.x, t = threadIdx.x;
  __shared__ float red[256];
  __shared__ float s_gmax;
  int lo = lower_bound_i(batch, N, g);
  int hi = lower_bound_i(batch, N, g + 1);
  float m = -3.4e38f;
  for (int i = lo + t; i < hi; i += 256) m = fmaxf(m, gate[i]);
  red[t] = m;
  __syncthreads();
  for (int off = 128; off; off >>= 1) {
    if (t < off) red[t] = fmaxf(red[t], red[t + off]);
    __syncthreads();
  }
  if (t == 0) s_gmax = red[0];
  __syncthreads();
  float gmax = s_gmax;
  __syncthreads();
  float ssum = 0.f;
  for (int i = lo + t; i < hi; i += 256) ssum += expf(gate[i] - gmax);
  red[t] = ssum;
  __syncthreads();
  for (int off = 128; off; off >>= 1) {
    if (t < off) red[t] += red[t + off];
    __syncthreads();
  }
  if (t == 0) {
    gmax_out[g] = gmax;
    ginv_out[g] = red[0] > 0.f ? 1.f / red[0] : 0.f;
  }
}

// K11: weighted partial feature sums; grid = B * POOL_S
__global__ __launch_bounds__(256) void pool_partial_kernel(
    const ushort_t* __restrict__ h2, const float* __restrict__ gate,
    const int* __restrict__ batch, const float* __restrict__ gmax_in,
    float* __restrict__ partial, int N) {
  int g = blockIdx.x / POOL_S, sub = blockIdx.x % POOL_S;
  int t = threadIdx.x;
  __shared__ float redx[256];
  __shared__ float redy[256];
  int lo = lower_bound_i(batch, N, g);
  int hi = lower_bound_i(batch, N, g + 1);
  int len = hi - lo;
  int chunk = (len + POOL_S - 1) / POOL_S;
  int a = lo + sub * chunk;
  int b = a + chunk < hi ? a + chunk : hi;
  float gmax = gmax_in[g];
  int p = t & 63, strm = t >> 6;
  const uint_t* h2u = (const uint_t*)h2;
  float accx = 0.f, accy = 0.f;
  int i = a + strm;
  for (; i + 8 <= b; i += 8) {
    float e0 = expf(gate[i] - gmax);
    float e1 = expf(gate[i + 4] - gmax);
    uint_t v0 = h2u[(size_t)i * 64 + p];
    uint_t v1 = h2u[(size_t)(i + 4) * 64 + p];
    accx += e0 * bf16_lo(v0) + e1 * bf16_lo(v1);
    accy += e0 * bf16_hi(v0) + e1 * bf16_hi(v1);
  }
  for (; i < b; i += 4) {
    float e = expf(gate[i] - gmax);
    uint_t v = h2u[(size_t)i * 64 + p];
    accx += e * bf16_lo(v);
    accy += e * bf16_hi(v);
  }
  redx[t] = accx;
  redy[t] = accy;
  __syncthreads();
  if (t < 64) {
    float px = redx[t] + redx[t + 64] + redx[t + 128] + redx[t + 192];
    float py = redy[t] + redy[t + 64] + redy[t + 128] + redy[t + 192];
    float* dst = partial + (size_t)blockIdx.x * 128;
    dst[2 * t] = px;
    dst[2 * t + 1] = py;
  }
}

// K12: reduce partials, * ginv, classifier
__global__ __launch_bounds__(128) void classify_kernel(
    const float* __restrict__ partial, const float* __restrict__ ginv,
    const float* __restrict__ Wc, const float* __restrict__ bc,
    float* __restrict__ out) {
  int g = blockIdx.x, t = threadIdx.x;
  __shared__ float pooled[128];
  float s = 0.f;
#pragma unroll
  for (int k = 0; k < POOL_S; ++k)
    s += partial[((size_t)g * POOL_S + k) * 128 + t];
  pooled[t] = s * ginv[g];
  __syncthreads();
  if (t < 16) {
    float o = bc[t];
    for (int ff = 0; ff < 128; ++ff) o = fmaf(pooled[ff], Wc[ff * 16 + t], o);
    out[g * 16 + t] = o;
  }
}

// ---------------- host launcher ----------------
extern "C" void kernel_launch(void* const* d_in, const int* in_sizes, int n_in,
                              void* d_out, int out_size, void* d_ws, size_t ws_size,
                              hipStream_t stream) {
  const float* x   = (const float*)d_in[0];
  const int*   ei  = (const int*)d_in[1];
  const int*   bat = (const int*)d_in[2];
  const float* W1  = (const float*)d_in[3];
  const float* b1  = (const float*)d_in[4];
  const float* g1  = (const float*)d_in[5];
  const float* be1 = (const float*)d_in[6];
  const float* W2  = (const float*)d_in[7];
  const float* b2  = (const float*)d_in[8];
  const float* g2  = (const float*)d_in[9];
  const float* be2 = (const float*)d_in[10];
  const float* Wg1 = (const float*)d_in[11];
  const float* bg1 = (const float*)d_in[12];
  const float* Wg2 = (const float*)d_in[13];
  const float* bg2 = (const float*)d_in[14];
  const float* Wc  = (const float*)d_in[15];
  const float* bc  = (const float*)d_in[16];

  const int N = in_sizes[0] / 128;
  const int E = in_sizes[1] / 2;
  const int B = out_size / 16;
  const int* src = ei;
  const int* dst = ei + E;

  const int Np = (N + 3) & ~3;
  const int Ep = (E + 3) & ~3;

  int* counts   = (int*)d_ws;               // Np (zeroed)
  int* rank     = counts + Np;              // Ep
  int* rs       = rank + Ep;                // Np + 4
  int* partials = rs + Np + 4;              // 128
  int* srcs     = partials + 128;           // Ep
  float* dinv   = (float*)(srcs + Ep);      // Np
  float* gatep  = dinv + Np;                // Np
  float* gmax   = gatep + Np;               // B
  float* ginv   = gmax + B;                 // B
  float* ppart  = ginv + B;                 // B*POOL_S*128
  ushort_t* Wt  = (ushort_t*)(ppart + (size_t)B * POOL_S * 128);  // 40960
  ushort_t* hs  = Wt + 40960;               // N*128 bf16
  ushort_t* h1  = hs + (size_t)128 * N;     // N*128 bf16 (h1, then h2)

  hipMemsetAsync(counts, 0, sizeof(int) * (size_t)Np, stream);

  const int nblk = (N + 1023) / 1024;
  const int cblk = (E + 255) / 256;
  count_prep_kernel<<<160 + cblk, 256, 0, stream>>>(dst, counts, rank, E, W1, W2, Wg1, Wt);
  scan_partials_kernel<<<nblk, 256, 0, stream>>>(counts, partials, N);
  scan_tops_kernel<<<1, 128, 0, stream>>>(partials, rs, nblk, N);
  scan_block_kernel<<<nblk, 256, 0, stream>>>(counts, partials, rs, dinv, N);

  // fused: place || GEMM1
  const int Gg = (N + 127) / 128;
  const int Gp = (E + 255) / 256;
  const int K = (Gp + Gg - 1) / Gg;
  gemm1_place_kernel<<<Gg * (K + 1), 256, 0, stream>>>(
      x, Wt, dinv, hs, N, src, dst, rs, rank, srcs, E, K);

  aggregate_ln_kernel<<<(N + 3) / 4, 256, 0, stream>>>(
      hs, rs, srcs, dinv, b1, g1, be1, h1, N);
  gemm_mfma_kernel<128, true, false, false><<<Gg, 256, 0, stream>>>(
      h1, Wt + 16384, nullptr, dinv, hs, N, nullptr, nullptr, nullptr);
  aggregate_ln_kernel<<<(N + 3) / 4, 256, 0, stream>>>(
      hs, rs, srcs, dinv, b2, g2, be2, h1, N);
  // gate GEMM with fused dot -> gate[N]
  gemm_mfma_kernel<64, false, true, true><<<Gg, 256, 0, stream>>>(
      h1, Wt + 32768, bg1, nullptr, nullptr, N, Wg2, bg2, gatep);
  // pooling, occupancy-shaped
  gate_stats_kernel<<<B, 256, 0, stream>>>(gatep, bat, gmax, ginv, N);
  pool_partial_kernel<<<B * POOL_S, 256, 0, stream>>>(h1, gatep, bat, gmax, ppart, N);
  classify_kernel<<<B, 128, 0, stream>>>(ppart, ginv, Wc, bc, (float*)d_out);
}